// Round 1
// baseline (602112.939 us; speedup 1.0000x reference)
//
#include <hip/hip_runtime.h>

#define AGENT __HIP_MEMORY_SCOPE_AGENT

constexpr int HIDDEN = 896;
constexpr int HALF   = 448;
constexpr int BINS   = 256;
constexpr int TSTEPS = 16384;
constexpr float INV_BINS    = 1.0f / 127.5f;
constexpr float INIT_SCALED = 128.0f * (1.0f / 127.5f) - 1.0f;

// counter slots (u32) at start of ws
#define C_BC 0   // coarse h_new done (56 HC WGs)
#define C_CC 1   // coarse pre done   (16 PC WGs)
#define C_DC 2   // coarse bins/argmax done (16 PC WGs)
#define C_EC 3   // fine h_new done   (56 HF WGs)
#define C_CF 4   // fine pre done     (16 PF WGs)
#define C_FF 5   // fine bins/argmax done (16 PF WGs)
#define C_RDY 15
#define RDY_MAGIC 0x13579BDFu

__device__ __forceinline__ void aput_f(float* p, float v) {
  __hip_atomic_store(p, v, __ATOMIC_RELAXED, AGENT);
}
__device__ __forceinline__ float aget_f(const float* p) {
  return __hip_atomic_load((float*)p, __ATOMIC_RELAXED, AGENT);
}
__device__ __forceinline__ void aput_u64(unsigned long long* p, unsigned long long v) {
  __hip_atomic_store(p, v, __ATOMIC_RELAXED, AGENT);
}
__device__ __forceinline__ unsigned long long aget_u64(const unsigned long long* p) {
  return __hip_atomic_load((unsigned long long*)p, __ATOMIC_RELAXED, AGENT);
}
__device__ __forceinline__ void arrive(unsigned int* c) {
  __hip_atomic_fetch_add(c, 1u, __ATOMIC_RELEASE, AGENT);
}
// tid0 spins with acquire; syncthreads broadcasts (acquire's cache-inv covers the CU)
__device__ __forceinline__ void spin_wg(unsigned int* c, unsigned int target) {
  if (threadIdx.x == 0) {
    while (__hip_atomic_load(c, __ATOMIC_ACQUIRE, AGENT) < target) { }
  }
  __syncthreads();
}

__device__ __forceinline__ float wave_sum(float s) {
  #pragma unroll
  for (int d = 1; d < 64; d <<= 1) s += __shfl_xor(s, d, 64);
  return s;
}

__device__ __forceinline__ float sigf(float x) { return 1.0f / (1.0f + __expf(-x)); }

// packed argmax key: higher logit wins; ties -> lower row index wins (matches jnp.argmax)
__device__ __forceinline__ unsigned long long pack_lg(float x, int row) {
  unsigned u = __float_as_uint(x);
  u = (u & 0x80000000u) ? ~u : (u | 0x80000000u);
  return ((unsigned long long)u << 32) | (unsigned)(255 - row);
}
__device__ __forceinline__ int dec_bin(unsigned long long v) {
  return 255 - (int)(unsigned)(v & 0xffffffffull);
}
__device__ __forceinline__ float dec_scaled(unsigned long long v) {
  return (float)dec_bin(v) * INV_BINS - 1.0f;
}

extern "C" __global__ void __launch_bounds__(256, 1)
wavernn_persist(const float* __restrict__ Wh,  const float* __restrict__ bh,
                const float* __restrict__ Wci, const float* __restrict__ Wfi,
                const float* __restrict__ cbias, const float* __restrict__ fbias,
                const float* __restrict__ pWc, const float* __restrict__ pBc,
                const float* __restrict__ bWc, const float* __restrict__ bBc,
                const float* __restrict__ pWf, const float* __restrict__ pBf,
                const float* __restrict__ bWf, const float* __restrict__ bBf,
                const float* __restrict__ h0,
                float* __restrict__ out, unsigned char* __restrict__ wsb)
{
  __shared__ unsigned long long sm[4];

  unsigned int* cnt = (unsigned int*)wsb;
  float* hbuf = (float*)(wsb + 64);                       // [2][896]
  float* prcb = (float*)(wsb + 64 + 2 * 896 * 4);         // [2][448]
  float* prfb = prcb + 2 * 448;                           // [2][448]
  unsigned long long* amc =
      (unsigned long long*)(wsb + 64 + 2 * 896 * 4 + 4 * 448 * 4); // [T]
  unsigned long long* amf = amc + TSTEPS;                          // [T]

  const int wg   = blockIdx.x;
  const int tid  = threadIdx.x;
  const int lane = tid & 63;
  const int wv   = tid >> 6;

  // ---------------- init (ws is re-poisoned before every launch) -------------
  if (wg == 0) {
    if (tid < 15) __hip_atomic_store(&cnt[tid], 0u, __ATOMIC_RELAXED, AGENT);
    for (int i = tid; i < HIDDEN; i += 256) aput_f(&hbuf[i], h0[i]);
    for (int i = tid; i < 2 * TSTEPS; i += 256) aput_u64(&amc[i], 0ull);
    __syncthreads();
    if (tid == 0)
      __hip_atomic_store(&cnt[C_RDY], RDY_MAGIC, __ATOMIC_RELEASE, AGENT);
  }

  if (wg < 112) {
    // =================== GRU gate workgroups (HC: 0-55, HF: 56-111) =========
    const bool fine = (wg >= 56);
    const int  i0   = (fine ? (wg - 56) : wg) * 8 + wv * 2; // first of 2 owned indices
    const int  rbase = fine ? 1344 : 0;
    const int  ncol  = fine ? 3 : 2;
    const float* Wi  = fine ? Wfi : Wci;
    const float* tbp = fine ? fbias : cbias;

    float wh[2][3][14], wi[2][3][3], hb[2][3], hprev[2];
    #pragma unroll
    for (int j = 0; j < 2; ++j) {
      const int i = i0 + j;
      #pragma unroll
      for (int g = 0; g < 3; ++g) {
        const int lrow = i + g * 448;       // local row in [0,1344)
        const int grow = rbase + lrow;      // row in Wh / bh
        #pragma unroll
        for (int k = 0; k < 14; ++k)
          wh[j][g][k] = Wh[(size_t)grow * 896 + k * 64 + lane];
        #pragma unroll
        for (int c = 0; c < 3; ++c)
          wi[j][g][c] = (c < ncol) ? Wi[lrow * ncol + c] : 0.0f;
        hb[j][g] = bh[grow];
      }
      hprev[j] = h0[(fine ? 448 : 0) + i];
    }

    if (tid == 0) {
      while (__hip_atomic_load(&cnt[C_RDY], __ATOMIC_ACQUIRE, AGENT) != RDY_MAGIC) { }
    }
    __syncthreads();

    for (int t = 0; t < TSTEPS; ++t) {
      const int p = t & 1, q = p ^ 1;

      // prefetch time-dependent biases (read-only; overlaps the spin below)
      float tb[2][3];
      #pragma unroll
      for (int j = 0; j < 2; ++j)
        #pragma unroll
        for (int g = 0; g < 3; ++g)
          tb[j][g] = tbp[(size_t)t * 1344 + (i0 + j) + g * 448];

      spin_wg(&cnt[C_FF], 16u * (unsigned)t);   // step t-1 fully done

      float c_prev, f_prev;
      if (t == 0) { c_prev = INIT_SCALED; f_prev = INIT_SCALED; }
      else {
        c_prev = dec_scaled(aget_u64(&amc[t - 1]));
        f_prev = dec_scaled(aget_u64(&amf[t - 1]));
      }

      float hv[14];
      #pragma unroll
      for (int k = 0; k < 14; ++k)
        hv[k] = aget_f(&hbuf[p * 896 + k * 64 + lane]);

      float acc[2][3];
      #pragma unroll
      for (int j = 0; j < 2; ++j)
        #pragma unroll
        for (int g = 0; g < 3; ++g) {
          float s = 0.f;
          #pragma unroll
          for (int k = 0; k < 14; ++k) s = fmaf(wh[j][g][k], hv[k], s);
          acc[j][g] = wave_sum(s) + hb[j][g];   // hp row (incl. hidden bias)
        }

      if (!fine) {
        #pragma unroll
        for (int j = 0; j < 2; ++j) {
          const float pr = tb[j][0] + wi[j][0][0] * c_prev + wi[j][0][1] * f_prev;
          const float pu = tb[j][1] + wi[j][1][0] * c_prev + wi[j][1][1] * f_prev;
          const float pn = tb[j][2] + wi[j][2][0] * c_prev + wi[j][2][1] * f_prev;
          const float r = sigf(pr + acc[j][0]);
          const float u = sigf(pu + acc[j][1]);
          const float n = tanhf(pn + r * acc[j][2]);
          const float hn = u * (hprev[j] - n) + n;
          hprev[j] = hn;
          if (lane == 0) aput_f(&hbuf[q * 896 + i0 + j], hn);
        }
        __syncthreads();
        if (tid == 0) arrive(&cnt[C_BC]);
      } else {
        float lin[2][3];
        #pragma unroll
        for (int j = 0; j < 2; ++j)
          #pragma unroll
          for (int g = 0; g < 3; ++g)
            lin[j][g] = tb[j][g] + wi[j][g][0] * c_prev + wi[j][g][1] * f_prev;

        spin_wg(&cnt[C_DC], 16u * (unsigned)(t + 1));   // coarse argmax ready
        const unsigned long long pc = aget_u64(&amc[t]);
        if (wg == 56 && tid == 0) out[t] = (float)dec_bin(pc);  // out_c[t]
        const float csc = dec_scaled(pc);

        #pragma unroll
        for (int j = 0; j < 2; ++j) {
          const float r = sigf(lin[j][0] + wi[j][0][2] * csc + acc[j][0]);
          const float u = sigf(lin[j][1] + wi[j][1][2] * csc + acc[j][1]);
          const float n = tanhf(lin[j][2] + wi[j][2][2] * csc + r * acc[j][2]);
          const float hn = u * (hprev[j] - n) + n;
          hprev[j] = hn;
          if (lane == 0) aput_f(&hbuf[q * 896 + 448 + i0 + j], hn);
        }
        __syncthreads();
        if (tid == 0) arrive(&cnt[C_EC]);
      }
    }

    // final hidden state -> out[2T ..)
    if (lane == 0) {
      out[2 * TSTEPS + (fine ? 448 : 0) + i0]     = hprev[0];
      out[2 * TSTEPS + (fine ? 448 : 0) + i0 + 1] = hprev[1];
    }

  } else {
    // ============== output-layer workgroups (PC: 112-127, PF: 128-143) ======
    const bool fg = (wg >= 128);
    const int  wl = ((wg - (fg ? 128 : 112)) << 2) + wv;   // 0..63
    const float* pW = fg ? pWf : pWc;
    const float* pB = fg ? pBf : pBc;
    const float* bW = fg ? bWf : bWc;
    const float* bB = fg ? bBf : bBc;
    float* preb = fg ? prfb : prcb;
    unsigned long long* am = fg ? amf : amc;
    unsigned int* cin  = fg ? &cnt[C_EC] : &cnt[C_BC];
    unsigned int* cmid = fg ? &cnt[C_CF] : &cnt[C_CC];
    unsigned int* cout = fg ? &cnt[C_FF] : &cnt[C_DC];
    const int hoff = fg ? 448 : 0;

    float wpre[7][7], bpre[7], wbin[4][7], bbin[4];
    #pragma unroll
    for (int r = 0; r < 7; ++r) {
      const int row = wl * 7 + r;
      #pragma unroll
      for (int k = 0; k < 7; ++k) wpre[r][k] = pW[row * 448 + k * 64 + lane];
      bpre[r] = pB[row];
    }
    #pragma unroll
    for (int r = 0; r < 4; ++r) {
      const int row = wl * 4 + r;
      #pragma unroll
      for (int k = 0; k < 7; ++k) wbin[r][k] = bW[row * 448 + k * 64 + lane];
      bbin[r] = bB[row];
    }

    if (tid == 0) {
      while (__hip_atomic_load(&cnt[C_RDY], __ATOMIC_ACQUIRE, AGENT) != RDY_MAGIC) { }
    }
    __syncthreads();

    for (int t = 0; t < TSTEPS; ++t) {
      const int p = t & 1, q = p ^ 1;

      spin_wg(cin, 56u * (unsigned)(t + 1));   // h_new half ready
      float hv[7];
      #pragma unroll
      for (int k = 0; k < 7; ++k)
        hv[k] = aget_f(&hbuf[q * 896 + hoff + k * 64 + lane]);

      #pragma unroll
      for (int r = 0; r < 7; ++r) {
        float s = 0.f;
        #pragma unroll
        for (int k = 0; k < 7; ++k) s = fmaf(wpre[r][k], hv[k], s);
        s = fmaxf(wave_sum(s) + bpre[r], 0.f);
        if (lane == 0) aput_f(&preb[p * 448 + wl * 7 + r], s);
      }
      __syncthreads();
      if (tid == 0) arrive(cmid);

      spin_wg(cmid, 16u * (unsigned)(t + 1));  // full pre vector ready
      float pv[7];
      #pragma unroll
      for (int k = 0; k < 7; ++k)
        pv[k] = aget_f(&preb[p * 448 + k * 64 + lane]);

      unsigned long long best = 0ull;
      #pragma unroll
      for (int r = 0; r < 4; ++r) {
        float s = 0.f;
        #pragma unroll
        for (int k = 0; k < 7; ++k) s = fmaf(wbin[r][k], pv[k], s);
        s = wave_sum(s) + bbin[r];
        const unsigned long long pk = pack_lg(s, wl * 4 + r);
        best = (pk > best) ? pk : best;
      }
      if (lane == 0) sm[wv] = best;
      __syncthreads();
      if (tid == 0) {
        unsigned long long m = sm[0];
        if (sm[1] > m) m = sm[1];
        if (sm[2] > m) m = sm[2];
        if (sm[3] > m) m = sm[3];
        __hip_atomic_fetch_max(&am[t], m, __ATOMIC_RELAXED, AGENT);
        arrive(cout);
      }
      // fine group leader writes out_f[t] once all 16 argmax contributions landed
      if (fg && wg == 128 && tid == 0) {
        while (__hip_atomic_load(cout, __ATOMIC_ACQUIRE, AGENT) <
               16u * (unsigned)(t + 1)) { }
        out[TSTEPS + t] = (float)dec_bin(aget_u64(&am[t]));
      }
    }
  }
}

extern "C" void kernel_launch(void* const* d_in, const int* in_sizes, int n_in,
                              void* d_out, int out_size, void* d_ws, size_t ws_size,
                              hipStream_t stream) {
  (void)in_sizes; (void)n_in; (void)out_size; (void)ws_size;
  wavernn_persist<<<144, 256, 0, stream>>>(
      (const float*)d_in[0],  (const float*)d_in[1],  (const float*)d_in[2],
      (const float*)d_in[3],  (const float*)d_in[4],  (const float*)d_in[5],
      (const float*)d_in[6],  (const float*)d_in[7],  (const float*)d_in[8],
      (const float*)d_in[9],  (const float*)d_in[10], (const float*)d_in[11],
      (const float*)d_in[12], (const float*)d_in[13], (const float*)d_in[14],
      (float*)d_out, (unsigned char*)d_ws);
}

// Round 2
// 297145.435 us; speedup vs baseline: 2.0263x; 2.0263x over previous
//
#include <hip/hip_runtime.h>

#define AGENT __HIP_MEMORY_SCOPE_AGENT

constexpr int HIDDEN = 896;
constexpr int HALF   = 448;
constexpr int TSTEPS = 16384;
constexpr float INV_BINS    = 1.0f / 127.5f;
constexpr float INIT_SCALED = 128.0f * (1.0f / 127.5f) - 1.0f;

// ws layout in u64 units:
//   AM slots  [half][parity][16] stride 8 u64 (64B padded)  : 512 u64
//   HBUF      [parity][896]   (tag<<32 | f32)               : 1792 u64
//   PRE       [half][parity][448] (tag<<32 | f32)           : 1792 u64
constexpr int AM_BASE  = 0;
constexpr int HB_BASE  = 512;
constexpr int PRE_BASE = 2304;   // total 4096 u64 = 32 KiB

__device__ __forceinline__ unsigned long long aget(const unsigned long long* p) {
  return __hip_atomic_load((unsigned long long*)p, __ATOMIC_RELAXED, AGENT);
}
__device__ __forceinline__ void aput(unsigned long long* p, unsigned long long v) {
  __hip_atomic_store(p, v, __ATOMIC_RELAXED, AGENT);
}
__device__ __forceinline__ float wave_sum(float s) {
  #pragma unroll
  for (int d = 1; d < 64; d <<= 1) s += __shfl_xor(s, d, 64);
  return s;
}
__device__ __forceinline__ float sigf(float x) { return 1.0f / (1.0f + __expf(-x)); }
__device__ __forceinline__ unsigned long long u64max(unsigned long long a, unsigned long long b) {
  return a > b ? a : b;
}
// packed partial-argmax slot: [logit_key:32 | tag:16 | (255-row):8]
__device__ __forceinline__ unsigned long long pack_key(float x, int row, unsigned tag) {
  unsigned u = __float_as_uint(x);
  u = (u & 0x80000000u) ? ~u : (u | 0x80000000u);
  return ((unsigned long long)u << 32) |
         ((unsigned long long)(tag & 0xFFFFu) << 8) |
         (unsigned)(255 - row);
}
__device__ __forceinline__ int slot_bin(unsigned long long v) { return 255 - (int)(v & 0xFFull); }
__device__ __forceinline__ float slot_scaled(unsigned long long v) {
  return (float)slot_bin(v) * INV_BINS - 1.0f;
}

extern "C" __global__ void __launch_bounds__(256, 1)
wavernn_persist(const float* __restrict__ Wh,  const float* __restrict__ bh,
                const float* __restrict__ Wci, const float* __restrict__ Wfi,
                const float* __restrict__ cbias, const float* __restrict__ fbias,
                const float* __restrict__ pWc, const float* __restrict__ pBc,
                const float* __restrict__ bWc, const float* __restrict__ bBc,
                const float* __restrict__ pWf, const float* __restrict__ pBf,
                const float* __restrict__ bWf, const float* __restrict__ bBf,
                const float* __restrict__ h0,
                float* __restrict__ out, unsigned long long* __restrict__ ws)
{
  const int wg   = blockIdx.x;
  const int tid  = threadIdx.x;
  const int lane = tid & 63;
  const int wv   = tid >> 6;

  if (wg < 56) {
    // ================= GRU workgroups: coarse 0-27, fine 28-55 ==============
    const int half = (wg >= 28) ? 1 : 0;
    const int wid  = wg - 28 * half;
    const int gw   = wid * 4 + wv;        // 0..111 per half
    const int i0   = gw * 4;              // 4 owned h-units
    const int ncol = half ? 3 : 2;
    const float* Wi  = half ? Wfi : Wci;
    const float* tbp = half ? fbias : cbias;

    float wh[4][3][14], wi[4][3][3], hb[4][3], hprev[4];
    #pragma unroll
    for (int j = 0; j < 4; ++j) {
      const int i = i0 + j;
      #pragma unroll
      for (int g = 0; g < 3; ++g) {
        const int lrow = g * 448 + i;
        const int grow = half * 1344 + lrow;
        #pragma unroll
        for (int k = 0; k < 14; ++k)
          wh[j][g][k] = Wh[(size_t)grow * 896 + k * 64 + lane];
        #pragma unroll
        for (int c = 0; c < 3; ++c)
          wi[j][g][c] = (c < ncol) ? Wi[lrow * ncol + c] : 0.0f;
        hb[j][g] = bh[grow];
      }
      hprev[j] = h0[half * 448 + i];
    }

    for (int t = 0; t < TSTEPS; ++t) {
      // streaming per-step biases: issue early (HBM latency hides under polls)
      float tb[4][3];
      #pragma unroll
      for (int j = 0; j < 4; ++j)
        #pragma unroll
        for (int g = 0; g < 3; ++g)
          tb[j][g] = tbp[(size_t)t * 1344 + g * 448 + (i0 + j)];

      // ---- phase A: full h(t-1), self-tagged poll; then hp = Wh @ h -------
      float hv[14];
      if (t == 0) {
        #pragma unroll
        for (int k = 0; k < 14; ++k) hv[k] = h0[k * 64 + lane];
      } else {
        const unsigned tagA = (unsigned)t;  // h(t-1) carries tag t
        unsigned long long* hbp = ws + HB_BASE + (size_t)((t - 1) & 1) * 896;
        for (;;) {
          unsigned long long v[14]; bool ok = true;
          #pragma unroll
          for (int k = 0; k < 14; ++k) v[k] = aget(hbp + k * 64 + lane);
          #pragma unroll
          for (int k = 0; k < 14; ++k) ok &= ((unsigned)(v[k] >> 32) == tagA);
          if (__all(ok)) {
            #pragma unroll
            for (int k = 0; k < 14; ++k) hv[k] = __uint_as_float((unsigned)v[k]);
            break;
          }
        }
      }

      float acc[4][3];
      #pragma unroll
      for (int j = 0; j < 4; ++j)
        #pragma unroll
        for (int g = 0; g < 3; ++g) {
          float s = 0.f;
          #pragma unroll
          for (int k = 0; k < 14; ++k) s = fmaf(wh[j][g][k], hv[k], s);
          acc[j][g] = wave_sum(s) + hb[j][g];
        }

      // ---- phase B: argmax slots, gates, publish h ------------------------
      float c_prev = INIT_SCALED, f_prev = INIT_SCALED;
      if (!half) {
        if (t >= 1) {
          const unsigned tagB = (unsigned)t & 0xFFFFu;       // am(t-1)
          const int par = (t - 1) & 1;
          unsigned long long* sp = ws + AM_BASE;
          const bool need = lane < 32;
          if (lane < 16)      sp = ws + AM_BASE + ((size_t)(2 + par) * 16 + lane) * 8;        // fine
          else if (lane < 32) sp = ws + AM_BASE + ((size_t)par * 16 + (lane - 16)) * 8;       // coarse
          unsigned long long rv = 0;
          for (;;) {
            if (need) rv = aget(sp);
            bool ok = !need || (((unsigned)(rv >> 8) & 0xFFFFu) == tagB);
            if (__all(ok)) break;
          }
          #pragma unroll
          for (int d = 1; d < 16; d <<= 1) rv = u64max(rv, __shfl_xor(rv, d, 64));
          const unsigned long long vf = __shfl(rv, 0, 64);
          const unsigned long long vc = __shfl(rv, 16, 64);
          f_prev = slot_scaled(vf);
          c_prev = slot_scaled(vc);
          if (wg == 0 && tid == 0) out[TSTEPS + (t - 1)] = (float)slot_bin(vf);
        }
        #pragma unroll
        for (int j = 0; j < 4; ++j) {
          const float r = sigf(tb[j][0] + wi[j][0][0] * c_prev + wi[j][0][1] * f_prev + acc[j][0]);
          const float u = sigf(tb[j][1] + wi[j][1][0] * c_prev + wi[j][1][1] * f_prev + acc[j][1]);
          const float n = tanhf(tb[j][2] + wi[j][2][0] * c_prev + wi[j][2][1] * f_prev + r * acc[j][2]);
          const float hn = u * (hprev[j] - n) + n;
          hprev[j] = hn;
          if (lane == 0)
            aput(ws + HB_BASE + (size_t)(t & 1) * 896 + i0 + j,
                 ((unsigned long long)(unsigned)(t + 1) << 32) | __float_as_uint(hn));
        }
      } else {
        // fine: poll coarse am(t) [tag t+1] and (t>=1) both am(t-1) [tag t]
        const int parT = t & 1, parP = (t - 1) & 1;
        const unsigned tagT = (unsigned)(t + 1) & 0xFFFFu;
        const unsigned tagP = (unsigned)t & 0xFFFFu;
        unsigned long long* sp = ws + AM_BASE;
        bool need = false; unsigned mytag = 0;
        if (lane < 16) {
          sp = ws + AM_BASE + ((size_t)parT * 16 + lane) * 8;              // coarse(t)
          need = true; mytag = tagT;
        } else if (t >= 1 && lane < 32) {
          sp = ws + AM_BASE + ((size_t)parP * 16 + (lane - 16)) * 8;       // coarse(t-1)
          need = true; mytag = tagP;
        } else if (t >= 1 && lane < 48) {
          sp = ws + AM_BASE + ((size_t)(2 + parP) * 16 + (lane - 32)) * 8; // fine(t-1)
          need = true; mytag = tagP;
        }
        unsigned long long rv = 0;
        for (;;) {
          if (need) rv = aget(sp);
          bool ok = !need || (((unsigned)(rv >> 8) & 0xFFFFu) == mytag);
          if (__all(ok)) break;
        }
        #pragma unroll
        for (int d = 1; d < 16; d <<= 1) rv = u64max(rv, __shfl_xor(rv, d, 64));
        const unsigned long long vct = __shfl(rv, 0, 64);
        const float csc = slot_scaled(vct);
        if (t >= 1) {
          c_prev = slot_scaled(__shfl(rv, 16, 64));
          f_prev = slot_scaled(__shfl(rv, 32, 64));
        }
        if (wg == 28 && tid == 0) out[t] = (float)slot_bin(vct);
        #pragma unroll
        for (int j = 0; j < 4; ++j) {
          const float r = sigf(tb[j][0] + wi[j][0][0] * c_prev + wi[j][0][1] * f_prev + wi[j][0][2] * csc + acc[j][0]);
          const float u = sigf(tb[j][1] + wi[j][1][0] * c_prev + wi[j][1][1] * f_prev + wi[j][1][2] * csc + acc[j][1]);
          const float n = tanhf(tb[j][2] + wi[j][2][0] * c_prev + wi[j][2][1] * f_prev + wi[j][2][2] * csc + r * acc[j][2]);
          const float hn = u * (hprev[j] - n) + n;
          hprev[j] = hn;
          if (lane == 0)
            aput(ws + HB_BASE + (size_t)(t & 1) * 896 + 448 + i0 + j,
                 ((unsigned long long)(unsigned)(t + 1) << 32) | __float_as_uint(hn));
        }
      }
    }

    // epilogue: last fine sample + final hidden state
    if (wg == 0 && wv == 0) {
      const unsigned tagL = 16384u & 0xFFFFu;
      unsigned long long* sp = ws + AM_BASE + ((size_t)(2 + 1) * 16 + (lane & 15)) * 8;
      const bool need = lane < 16;
      unsigned long long rv = 0;
      for (;;) {
        if (need) rv = aget(sp);
        bool ok = !need || (((unsigned)(rv >> 8) & 0xFFFFu) == tagL);
        if (__all(ok)) break;
      }
      #pragma unroll
      for (int d = 1; d < 16; d <<= 1) rv = u64max(rv, __shfl_xor(rv, d, 64));
      if (lane == 0) out[TSTEPS + 16383] = (float)slot_bin(rv);
    }
    if (lane == 0) {
      #pragma unroll
      for (int j = 0; j < 4; ++j)
        out[2 * TSTEPS + half * 448 + i0 + j] = hprev[j];
    }

  } else {
    // ============ output workgroups: coarse 56-71, fine 72-87 ===============
    const int half = (wg >= 72) ? 1 : 0;
    const int oid  = wg - (half ? 72 : 56);   // 0..15
    const int wl   = oid * 4 + wv;            // 0..63
    const float* pW = half ? pWf : pWc;
    const float* pB = half ? pBf : pBc;
    const float* bW = half ? bWf : bWc;
    const float* bB = half ? bBf : bBc;

    float wpre[7][7], bpre[7], wbin[4][7], bbin[4];
    #pragma unroll
    for (int r = 0; r < 7; ++r) {
      const int row = wl * 7 + r;
      #pragma unroll
      for (int k = 0; k < 7; ++k) wpre[r][k] = pW[row * 448 + k * 64 + lane];
      bpre[r] = pB[row];
    }
    #pragma unroll
    for (int r = 0; r < 4; ++r) {
      const int row = wl * 4 + r;
      #pragma unroll
      for (int k = 0; k < 7; ++k) wbin[r][k] = bW[row * 448 + k * 64 + lane];
      bbin[r] = bB[row];
    }

    __shared__ unsigned long long sm[4];

    for (int t = 0; t < TSTEPS; ++t) {
      const unsigned tag = (unsigned)(t + 1);

      // poll h_half(t) (self-tagged)
      unsigned long long* hbp = ws + HB_BASE + (size_t)(t & 1) * 896 + half * 448;
      float hv[7];
      for (;;) {
        unsigned long long v[7]; bool ok = true;
        #pragma unroll
        for (int k = 0; k < 7; ++k) v[k] = aget(hbp + k * 64 + lane);
        #pragma unroll
        for (int k = 0; k < 7; ++k) ok &= ((unsigned)(v[k] >> 32) == tag);
        if (__all(ok)) {
          #pragma unroll
          for (int k = 0; k < 7; ++k) hv[k] = __uint_as_float((unsigned)v[k]);
          break;
        }
      }

      // pre rows (7 per wave), publish self-tagged
      unsigned long long* prep = ws + PRE_BASE + (size_t)(half * 2 + (t & 1)) * 448;
      #pragma unroll
      for (int r = 0; r < 7; ++r) {
        float s = 0.f;
        #pragma unroll
        for (int k = 0; k < 7; ++k) s = fmaf(wpre[r][k], hv[k], s);
        s = fmaxf(wave_sum(s) + bpre[r], 0.f);
        if (lane == 0)
          aput(prep + wl * 7 + r, ((unsigned long long)tag << 32) | __float_as_uint(s));
      }

      // poll full pre vector, compute 16 bins, partial argmax
      float pv[7];
      for (;;) {
        unsigned long long v[7]; bool ok = true;
        #pragma unroll
        for (int k = 0; k < 7; ++k) v[k] = aget(prep + k * 64 + lane);
        #pragma unroll
        for (int k = 0; k < 7; ++k) ok &= ((unsigned)(v[k] >> 32) == tag);
        if (__all(ok)) {
          #pragma unroll
          for (int k = 0; k < 7; ++k) pv[k] = __uint_as_float((unsigned)v[k]);
          break;
        }
      }
      unsigned long long best = 0ull;
      #pragma unroll
      for (int r = 0; r < 4; ++r) {
        float s = 0.f;
        #pragma unroll
        for (int k = 0; k < 7; ++k) s = fmaf(wbin[r][k], pv[k], s);
        s = wave_sum(s) + bbin[r];
        best = u64max(best, pack_key(s, wl * 4 + r, tag));
      }
      if (lane == 0) sm[wv] = best;
      __syncthreads();
      if (tid == 0) {
        const unsigned long long m = u64max(u64max(sm[0], sm[1]), u64max(sm[2], sm[3]));
        aput(ws + AM_BASE + ((size_t)(half * 2 + (t & 1)) * 16 + oid) * 8, m);
      }
    }
  }
}

extern "C" void kernel_launch(void* const* d_in, const int* in_sizes, int n_in,
                              void* d_out, int out_size, void* d_ws, size_t ws_size,
                              hipStream_t stream) {
  (void)in_sizes; (void)n_in; (void)out_size; (void)ws_size;
  wavernn_persist<<<88, 256, 0, stream>>>(
      (const float*)d_in[0],  (const float*)d_in[1],  (const float*)d_in[2],
      (const float*)d_in[3],  (const float*)d_in[4],  (const float*)d_in[5],
      (const float*)d_in[6],  (const float*)d_in[7],  (const float*)d_in[8],
      (const float*)d_in[9],  (const float*)d_in[10], (const float*)d_in[11],
      (const float*)d_in[12], (const float*)d_in[13], (const float*)d_in[14],
      (float*)d_out, (unsigned long long*)d_ws);
}